// Round 3
// baseline (133.091 us; speedup 1.0000x reference)
//
#include <hip/hip_runtime.h>

#define EPSF 1e-10f

struct alignas(8) Node { int par; float c; };

typedef int   v4i __attribute__((ext_vector_type(4)));
typedef float v4f __attribute__((ext_vector_type(4)));

__device__ __forceinline__ float signed_log(float x) {
    float sg = (x > 0.f) ? 1.f : ((x < 0.f) ? -1.f : 0.f);
    return logf(fabsf(x) + EPSF) * sg;
}

// ---- Stage 1: per-CC sigmoid scores -----------------------------------------
__global__ void scores_kernel(const float* __restrict__ attrs,
                              const float* __restrict__ weight,
                              const float* __restrict__ bias,
                              float* __restrict__ scores, int num_cc) {
    int i = blockIdx.x * blockDim.x + threadIdx.x;
    if (i >= num_cc) return;
    const float* f = attrs + (long long)i * 15;
    float w[17];
#pragma unroll
    for (int k = 0; k < 17; ++k) w[k] = weight[k];
    float acc = bias[0];
    acc += w[0] * f[0] + w[1] * f[1] + w[2] * f[2] + w[3] * f[3];
    acc += w[4] * logf(f[4]);                      // log(area)
#pragma unroll
    for (int j = 0; j < 9; ++j) acc += w[5 + j] * signed_log(f[6 + j]);
    float lshape = sqrtf(f[7]) / (sqrtf(f[6]) + EPSF);
    acc += w[14] * lshape;
    acc += w[15] * cosf(f[5]);
    acc += w[16] * sinf(f[5]);
    __builtin_nontemporal_store(1.f / (1.f + expf(-acc)), &scores[i]);
}

// ---- Stage 2: per-pixel contribution packed with parent (4 px / thread) -----
__global__ void pack_kernel4(const v4f* __restrict__ diff4,
                             const v4i* __restrict__ parent4,
                             const v4i* __restrict__ cc4,
                             const float* __restrict__ scores,
                             v4i* __restrict__ packed2, int n4) {
    int i = blockIdx.x * blockDim.x + threadIdx.x;
    if (i >= n4) return;
    v4f d = __builtin_nontemporal_load(&diff4[i]);
    v4i p = __builtin_nontemporal_load(&parent4[i]);
    v4i c = __builtin_nontemporal_load(&cc4[i]);
    float s0 = scores[c.x], s1 = scores[c.y], s2 = scores[c.z], s3 = scores[c.w];
    v4i o0, o1;
    o0.x = p.x; o0.y = __float_as_int(d.x * s0);
    o0.z = p.y; o0.w = __float_as_int(d.y * s1);
    o1.x = p.z; o1.y = __float_as_int(d.z * s2);
    o1.z = p.w; o1.w = __float_as_int(d.w * s3);
    __builtin_nontemporal_store(o0, &packed2[2 * i]);
    __builtin_nontemporal_store(o1, &packed2[2 * i + 1]);
}

__global__ void pack_kernel(const float* __restrict__ diff,
                            const int* __restrict__ parent,
                            const int* __restrict__ cc_id,
                            const float* __restrict__ scores,
                            Node* __restrict__ packed, int lo, int n) {
    int i = lo + blockIdx.x * blockDim.x + threadIdx.x;
    if (i >= n) return;
    Node nd;
    nd.par = parent[i];
    nd.c = diff[i] * scores[cc_id[i]];
    packed[i] = nd;
}

// ---- Stage 3: range-staged chain walk (parent[i] < i) -----------------------

// Base range [0, range_end): full walk to root (parent of root == -1).
__global__ void walk_base(const Node* __restrict__ packed,
                          float* __restrict__ out, int range_end) {
    int i = blockIdx.x * blockDim.x + threadIdx.x;
    if (i >= range_end) return;
    long long raw = __builtin_nontemporal_load((const long long*)(packed + i));
    int cur = (int)(raw & 0xffffffffLL);
    float s = __int_as_float((int)(raw >> 32));
    while (cur >= 0) {
        Node nd = packed[cur];     // cached: region is small & hot
        s += nd.c;
        cur = nd.par;
    }
    __builtin_nontemporal_store(s, &out[i]);
}

// Phase [lo, hi): PX consecutive pixels per thread; branch-free interleaved
// chain stepping so PX independent gathers are in flight per latency.
template <int PX>
__global__ void walk_phaseN(const Node* __restrict__ packed,
                            float* __restrict__ out, int lo, int hi) {
    long long t = (long long)blockIdx.x * blockDim.x + threadIdx.x;
    int base = lo + (int)(t * PX);
    if (base >= hi) return;
    int cur[PX]; float s[PX];

    if (base + PX <= hi) {
#pragma unroll
        for (int k = 0; k < PX; k += 2) {
            v4i raw = __builtin_nontemporal_load((const v4i*)(packed + base + k));
            cur[k]     = raw.x; s[k]     = __int_as_float(raw.y);
            cur[k + 1] = raw.z; s[k + 1] = __int_as_float(raw.w);
        }
    } else {
#pragma unroll
        for (int k = 0; k < PX; ++k) {
            if (base + k < hi) { Node nd = packed[base + k]; cur[k] = nd.par; s[k] = nd.c; }
            else               { cur[k] = 0; s[k] = 0.f; }
        }
    }

    while (true) {
        bool any = false;
#pragma unroll
        for (int k = 0; k < PX; ++k) any |= (cur[k] >= lo);
        if (!__any(any)) break;
#pragma unroll
        for (int k = 0; k < PX; ++k) {
            bool act = cur[k] >= lo;
            int idx = act ? cur[k] : lo;       // dummy hot line when inactive
            Node nd = packed[idx];
            s[k]  += act ? nd.c : 0.f;
            cur[k] = act ? nd.par : cur[k];
        }
    }

    // cur[k] in [0, lo): finished values (stream-ordered prior kernels)
#pragma unroll
    for (int k = 0; k < PX; ++k) s[k] += out[cur[k]];

    if (base + PX <= hi) {
#pragma unroll
        for (int k = 0; k < PX; k += 4) {
            v4f o; o.x = s[k]; o.y = s[k + 1]; o.z = s[k + 2]; o.w = s[k + 3];
            __builtin_nontemporal_store(o, (v4f*)(out + base + k));
        }
    } else {
#pragma unroll
        for (int k = 0; k < PX; ++k)
            if (base + k < hi) out[base + k] = s[k];
    }
}

// Unpacked fallbacks (only if ws too small for the packed array).
__global__ void walk_base2(const int* __restrict__ parent,
                           const float* __restrict__ contrib,
                           float* __restrict__ out, int range_end) {
    int i = blockIdx.x * blockDim.x + threadIdx.x;
    if (i >= range_end) return;
    float s = 0.f;
    int cur = i;
    while (cur >= 0) { s += contrib[cur]; cur = parent[cur]; }
    out[i] = s;
}

__global__ void walk_phase2(const int* __restrict__ parent,
                            const float* __restrict__ contrib,
                            float* __restrict__ out, int lo, int hi) {
    int i = lo + blockIdx.x * blockDim.x + threadIdx.x;
    if (i >= hi) return;
    float s = 0.f;
    int cur = i;
    while (cur >= lo) { s += contrib[cur]; cur = parent[cur]; }
    s += out[cur];
    out[i] = s;
}

__global__ void contrib_kernel(const float* __restrict__ diff,
                               const int* __restrict__ cc_id,
                               const float* __restrict__ scores,
                               float* __restrict__ contrib, int n) {
    int i = blockIdx.x * blockDim.x + threadIdx.x;
    if (i >= n) return;
    contrib[i] = diff[i] * scores[cc_id[i]];
}

static inline int iminh(int a, int b) { return a < b ? a : b; }

extern "C" void kernel_launch(void* const* d_in, const int* in_sizes, int n_in,
                              void* d_out, int out_size, void* d_ws, size_t ws_size,
                              hipStream_t stream) {
    const float* diff   = (const float*)d_in[0];
    const float* attrs  = (const float*)d_in[1];
    const float* weight = (const float*)d_in[2];
    const float* bias   = (const float*)d_in[3];
    const int*   parent = (const int*)d_in[4];
    const int*   cc_id  = (const int*)d_in[5];
    float* out = (float*)d_out;

    const int n      = in_sizes[0];        // 2048*2048
    const int num_cc = in_sizes[1] / 15;   // 1<<20

    float* scores = (float*)d_ws;
    const size_t scores_bytes = (size_t)num_cc * sizeof(float);
    const size_t packed_need  = scores_bytes + (size_t)n * sizeof(Node);
    const bool use_packed = ws_size >= packed_need;

    const int TB = 256;
    scores_kernel<<<(num_cc + TB - 1) / TB, TB, 0, stream>>>(attrs, weight, bias, scores, num_cc);

    const int BASE   = 131072;             // [0, BASE): full walk (L2-resident)
    const int R2_MIN = 1 << 19;            // ranges >= 512K use ratio 2; below use ratio 4
    const int PX8_MIN = 1 << 20;           // phases with >=1M nodes use PX=8

    if (use_packed) {
        Node* packed = (Node*)((char*)d_ws + scores_bytes);
        if ((n & 3) == 0) {
            pack_kernel4<<<(n / 4 + TB - 1) / TB, TB, 0, stream>>>(
                (const v4f*)diff, (const v4i*)parent, (const v4i*)cc_id, scores, (v4i*)packed, n / 4);
        } else {
            pack_kernel<<<(n + TB - 1) / TB, TB, 0, stream>>>(diff, parent, cc_id, scores, packed, 0, n);
        }
        int base_end = iminh(BASE, n);
        walk_base<<<(base_end + TB - 1) / TB, TB, 0, stream>>>(packed, out, base_end);
        int lo = base_end;
        while (lo < n) {
            int ratio = (lo < R2_MIN) ? 4 : 2;
            long long hi_ll = (long long)lo * ratio;
            int hi = (hi_ll > n) ? n : (int)hi_ll;
            int cnt = hi - lo;
            if (cnt >= PX8_MIN) {
                long long threads = (cnt + 7) / 8;
                walk_phaseN<8><<<(int)((threads + TB - 1) / TB), TB, 0, stream>>>(packed, out, lo, hi);
            } else {
                long long threads = (cnt + 3) / 4;
                walk_phaseN<4><<<(int)((threads + TB - 1) / TB), TB, 0, stream>>>(packed, out, lo, hi);
            }
            lo = hi;
        }
    } else {
        float* contrib = (float*)((char*)d_ws + scores_bytes);
        contrib_kernel<<<(n + TB - 1) / TB, TB, 0, stream>>>(diff, cc_id, scores, contrib, n);
        int base_end = iminh(BASE, n);
        walk_base2<<<(base_end + TB - 1) / TB, TB, 0, stream>>>(parent, contrib, out, base_end);
        int lo = base_end;
        while (lo < n) {
            int ratio = (lo < R2_MIN) ? 4 : 2;
            long long hi_ll = (long long)lo * ratio;
            int hi = (hi_ll > n) ? n : (int)hi_ll;
            walk_phase2<<<((hi - lo) + TB - 1) / TB, TB, 0, stream>>>(parent, contrib, out, lo, hi);
            lo = hi;
        }
    }
}

// Round 4
// 123.799 us; speedup vs baseline: 1.0751x; 1.0751x over previous
//
#include <hip/hip_runtime.h>
#include <hip/hip_fp16.h>

#define EPSF 1e-10f

struct alignas(8) Node { int par; float c; };

typedef int      v4i  __attribute__((ext_vector_type(4)));
typedef float    v4f  __attribute__((ext_vector_type(4)));
typedef _Float16 h4   __attribute__((ext_vector_type(4)));

__device__ __forceinline__ float signed_log(float x) {
    float sg = (x > 0.f) ? 1.f : ((x < 0.f) ? -1.f : 0.f);
    return logf(fabsf(x) + EPSF) * sg;
}

// ---- Stage 1: per-CC sigmoid scores -----------------------------------------
__global__ void scores_kernel(const float* __restrict__ attrs,
                              const float* __restrict__ weight,
                              const float* __restrict__ bias,
                              float* __restrict__ scores, int num_cc) {
    int i = blockIdx.x * blockDim.x + threadIdx.x;
    if (i >= num_cc) return;
    const float* f = attrs + (long long)i * 15;
    float w[17];
#pragma unroll
    for (int k = 0; k < 17; ++k) w[k] = weight[k];
    float acc = bias[0];
    acc += w[0] * f[0] + w[1] * f[1] + w[2] * f[2] + w[3] * f[3];
    acc += w[4] * logf(f[4]);                      // log(area)
#pragma unroll
    for (int j = 0; j < 9; ++j) acc += w[5 + j] * signed_log(f[6 + j]);
    float lshape = sqrtf(f[7]) / (sqrtf(f[6]) + EPSF);
    acc += w[14] * lshape;
    acc += w[15] * cosf(f[5]);
    acc += w[16] * sinf(f[5]);
    __builtin_nontemporal_store(1.f / (1.f + expf(-acc)), &scores[i]);
}

// ---- Stage 2: per-pixel contribution packed with parent (4 px / thread) -----
__global__ void pack_kernel4(const v4f* __restrict__ diff4,
                             const v4i* __restrict__ parent4,
                             const v4i* __restrict__ cc4,
                             const float* __restrict__ scores,
                             v4i* __restrict__ packed2, int n4) {
    int i = blockIdx.x * blockDim.x + threadIdx.x;
    if (i >= n4) return;
    v4f d = __builtin_nontemporal_load(&diff4[i]);
    v4i p = __builtin_nontemporal_load(&parent4[i]);
    v4i c = __builtin_nontemporal_load(&cc4[i]);
    float s0 = scores[c.x], s1 = scores[c.y], s2 = scores[c.z], s3 = scores[c.w];
    v4i o0, o1;
    o0.x = p.x; o0.y = __float_as_int(d.x * s0);
    o0.z = p.y; o0.w = __float_as_int(d.y * s1);
    o1.x = p.z; o1.y = __float_as_int(d.z * s2);
    o1.z = p.w; o1.w = __float_as_int(d.w * s3);
    __builtin_nontemporal_store(o0, &packed2[2 * i]);
    __builtin_nontemporal_store(o1, &packed2[2 * i + 1]);
}

__global__ void pack_kernel(const float* __restrict__ diff,
                            const int* __restrict__ parent,
                            const int* __restrict__ cc_id,
                            const float* __restrict__ scores,
                            Node* __restrict__ packed, int lo, int n) {
    int i = lo + blockIdx.x * blockDim.x + threadIdx.x;
    if (i >= n) return;
    Node nd;
    nd.par = parent[i];
    nd.c = diff[i] * scores[cc_id[i]];
    packed[i] = nd;
}

// ---- Stage 3: range-staged chain walk (parent[i] < i) -----------------------

// Base range [0, range_end): full walk to root (parent of root == -1).
// Writes fp32 out + fp16 shadow (shadow is the gather target for later phases).
template <bool SH>
__global__ void walk_base(const Node* __restrict__ packed,
                          float* __restrict__ out,
                          _Float16* __restrict__ shadow, int range_end) {
    int i = blockIdx.x * blockDim.x + threadIdx.x;
    if (i >= range_end) return;
    long long raw = __builtin_nontemporal_load((const long long*)(packed + i));
    int cur = (int)(raw & 0xffffffffLL);
    float s = __int_as_float((int)(raw >> 32));
    while (cur >= 0) {
        Node nd = packed[cur];     // cached: region is small & hot (L2)
        s += nd.c;
        cur = nd.par;
    }
    __builtin_nontemporal_store(s, &out[i]);
    if (SH) __builtin_nontemporal_store((_Float16)s, &shadow[i]);
}

// Phase [lo, hi): PX consecutive pixels per thread; branch-free interleaved
// chain stepping. Finished-ancestor add reads the fp16 shadow (L2-resident).
template <int PX, bool SH>
__global__ void walk_phaseN(const Node* __restrict__ packed,
                            float* __restrict__ out,
                            _Float16* __restrict__ shadow, int lo, int hi) {
    long long t = (long long)blockIdx.x * blockDim.x + threadIdx.x;
    int base = lo + (int)(t * PX);
    if (base >= hi) return;
    int cur[PX]; float s[PX];

    const bool full = (base + PX <= hi);
    if (full) {
#pragma unroll
        for (int k = 0; k < PX; k += 2) {
            v4i raw = __builtin_nontemporal_load((const v4i*)(packed + base + k));
            cur[k]     = raw.x; s[k]     = __int_as_float(raw.y);
            cur[k + 1] = raw.z; s[k + 1] = __int_as_float(raw.w);
        }
    } else {
#pragma unroll
        for (int k = 0; k < PX; ++k) {
            if (base + k < hi) { Node nd = packed[base + k]; cur[k] = nd.par; s[k] = nd.c; }
            else               { cur[k] = 0; s[k] = 0.f; }
        }
    }

    while (true) {
        bool any = false;
#pragma unroll
        for (int k = 0; k < PX; ++k) any |= (cur[k] >= lo);
        if (!__any(any)) break;
#pragma unroll
        for (int k = 0; k < PX; ++k) {
            bool act = cur[k] >= lo;
            int idx = act ? cur[k] : lo;       // dummy hot line when inactive
            Node nd = packed[idx];
            s[k]  += act ? nd.c : 0.f;
            cur[k] = act ? nd.par : cur[k];
        }
    }

    // cur[k] in [0, lo): finished (stream-ordered kernels). Shadow = fp16 copy
    // of out[0,lo): half the footprint -> per-XCD L2 resident -> low latency.
#pragma unroll
    for (int k = 0; k < PX; ++k)
        s[k] += SH ? (float)shadow[cur[k]] : out[cur[k]];

    if (full) {
#pragma unroll
        for (int k = 0; k < PX; k += 4) {
            v4f o; o.x = s[k]; o.y = s[k + 1]; o.z = s[k + 2]; o.w = s[k + 3];
            __builtin_nontemporal_store(o, (v4f*)(out + base + k));
            if (SH) {
                h4 hv; hv.x = (_Float16)s[k]; hv.y = (_Float16)s[k + 1];
                hv.z = (_Float16)s[k + 2];    hv.w = (_Float16)s[k + 3];
                __builtin_nontemporal_store(hv, (h4*)(shadow + base + k));
            }
        }
    } else {
#pragma unroll
        for (int k = 0; k < PX; ++k)
            if (base + k < hi) {
                out[base + k] = s[k];
                if (SH) shadow[base + k] = (_Float16)s[k];
            }
    }
}

// Unpacked fallbacks (only if ws too small for the packed array).
__global__ void walk_base2(const int* __restrict__ parent,
                           const float* __restrict__ contrib,
                           float* __restrict__ out, int range_end) {
    int i = blockIdx.x * blockDim.x + threadIdx.x;
    if (i >= range_end) return;
    float s = 0.f;
    int cur = i;
    while (cur >= 0) { s += contrib[cur]; cur = parent[cur]; }
    out[i] = s;
}

__global__ void walk_phase2(const int* __restrict__ parent,
                            const float* __restrict__ contrib,
                            float* __restrict__ out, int lo, int hi) {
    int i = lo + blockIdx.x * blockDim.x + threadIdx.x;
    if (i >= hi) return;
    float s = 0.f;
    int cur = i;
    while (cur >= lo) { s += contrib[cur]; cur = parent[cur]; }
    s += out[cur];
    out[i] = s;
}

__global__ void contrib_kernel(const float* __restrict__ diff,
                               const int* __restrict__ cc_id,
                               const float* __restrict__ scores,
                               float* __restrict__ contrib, int n) {
    int i = blockIdx.x * blockDim.x + threadIdx.x;
    if (i >= n) return;
    contrib[i] = diff[i] * scores[cc_id[i]];
}

static inline int iminh(int a, int b) { return a < b ? a : b; }

extern "C" void kernel_launch(void* const* d_in, const int* in_sizes, int n_in,
                              void* d_out, int out_size, void* d_ws, size_t ws_size,
                              hipStream_t stream) {
    const float* diff   = (const float*)d_in[0];
    const float* attrs  = (const float*)d_in[1];
    const float* weight = (const float*)d_in[2];
    const float* bias   = (const float*)d_in[3];
    const int*   parent = (const int*)d_in[4];
    const int*   cc_id  = (const int*)d_in[5];
    float* out = (float*)d_out;

    const int n      = in_sizes[0];        // 2048*2048
    const int num_cc = in_sizes[1] / 15;   // 1<<20

    float* scores = (float*)d_ws;
    const size_t scores_bytes = (size_t)num_cc * sizeof(float);
    const size_t packed_bytes = (size_t)n * sizeof(Node);
    const size_t shadow_bytes = (size_t)n * sizeof(_Float16);
    const bool use_packed = ws_size >= scores_bytes + packed_bytes;
    const bool use_shadow = ws_size >= scores_bytes + packed_bytes + shadow_bytes;

    const int TB = 256;
    scores_kernel<<<(num_cc + TB - 1) / TB, TB, 0, stream>>>(attrs, weight, bias, scores, num_cc);

    const int BASE = 131072;               // [0, BASE): full walk (L2-resident)

    if (use_packed) {
        Node* packed = (Node*)((char*)d_ws + scores_bytes);
        _Float16* shadow = use_shadow ? (_Float16*)((char*)d_ws + scores_bytes + packed_bytes)
                                      : (_Float16*)nullptr;
        if ((n & 3) == 0) {
            pack_kernel4<<<(n / 4 + TB - 1) / TB, TB, 0, stream>>>(
                (const v4f*)diff, (const v4i*)parent, (const v4i*)cc_id, scores, (v4i*)packed, n / 4);
        } else {
            pack_kernel<<<(n + TB - 1) / TB, TB, 0, stream>>>(diff, parent, cc_id, scores, packed, 0, n);
        }
        int base_end = iminh(BASE, n);
        if (use_shadow)
            walk_base<true><<<(base_end + TB - 1) / TB, TB, 0, stream>>>(packed, out, shadow, base_end);
        else
            walk_base<false><<<(base_end + TB - 1) / TB, TB, 0, stream>>>(packed, out, shadow, base_end);
        int lo = base_end;
        while (lo < n) {                   // ratio-2 phases throughout
            long long hi_ll = (long long)lo * 2;
            int hi = (hi_ll > n) ? n : (int)hi_ll;
            int cnt = hi - lo;
            long long threads = (cnt + 3) / 4;
            int grid = (int)((threads + TB - 1) / TB);
            if (use_shadow)
                walk_phaseN<4, true><<<grid, TB, 0, stream>>>(packed, out, shadow, lo, hi);
            else
                walk_phaseN<4, false><<<grid, TB, 0, stream>>>(packed, out, shadow, lo, hi);
            lo = hi;
        }
    } else {
        float* contrib = (float*)((char*)d_ws + scores_bytes);
        contrib_kernel<<<(n + TB - 1) / TB, TB, 0, stream>>>(diff, cc_id, scores, contrib, n);
        int base_end = iminh(BASE, n);
        walk_base2<<<(base_end + TB - 1) / TB, TB, 0, stream>>>(parent, contrib, out, base_end);
        int lo = base_end;
        while (lo < n) {
            long long hi_ll = (long long)lo * 2;
            int hi = (hi_ll > n) ? n : (int)hi_ll;
            walk_phase2<<<((hi - lo) + TB - 1) / TB, TB, 0, stream>>>(parent, contrib, out, lo, hi);
            lo = hi;
        }
    }
}